// Round 3
// baseline (85.250 us; speedup 1.0000x reference)
//
#include <hip/hip_runtime.h>
#include <math.h>

// Problem constants (from reference setup_inputs): B=8192, P=60, C=15, D=200
constexpr int kP  = 60;
constexpr int kD  = 200;
constexpr int kC  = 15;
constexpr int PPB = 256;   // pairs per block

// Closed form of the 2-qubit circuit (re-derived & limit-checked round 2):
//   z0 = cos(ty)*cos(x0) - sin(ty)*cos(tz)*sin(x0)*sin(x1)
//   z1 = cos(ty)*cos(x1)                  (x0-independent; class-dep via ty)
//   out = (z+1)/2
// Output layout [B, P*2, C] flat: pair g owns floats [30g, 30g+30):
//   e in [0,15):  0.5 + A[e]*cos(x0) - B[e]*sin(x0)*sin(x1)
//   e in [15,30): 0.5 + A[e-15]*cos(x1)
// with A[c]=0.5*cos(ty_c), B[c]=0.5*sin(ty_c)*cos(tz_c).
__global__ __launch_bounds__(256)
void fuzzy_quantum_kernel(const float* __restrict__ x,          // [B, D]
                          const int*   __restrict__ pairs_idx,  // [B, P, 2]
                          const float* __restrict__ rz,         // [C]
                          const float* __restrict__ ry,         // [C]
                          float* __restrict__ out,              // [B, P*2, C]
                          int npairs)                           // B*P
{
    __shared__ float4 s_pair[PPB];   // {cos x0, cos x1, sin x0*sin x1, 0} per pair
    __shared__ float2 s_T[32];       // r in [0,30): {A[r%15], r<15 ? B[r] : 0}

    const int t = threadIdx.x;

    // per-element class table: one ds_read_b64 per output element later
    if (t < 30) {
        const int c = (t < kC) ? t : t - kC;
        float sy, cy;
        sincosf(ry[c], &sy, &cy);
        s_T[t] = make_float2(0.5f * cy,
                             (t < kC) ? (0.5f * sy * cosf(rz[c])) : 0.0f);
    }

    // ---- phase 1: one pair per thread ----
    const int g = blockIdx.x * PPB + t;
    if (g < npairs) {
        const int2 ii = ((const int2*)pairs_idx)[g];   // coalesced 8B load
        const int b = g / kP;
        const float x0 = x[b * kD + ii.x];
        const float x1 = x[b * kD + ii.y];
        float s0, c0, s1, c1;
        sincosf(x0, &s0, &c0);
        sincosf(x1, &s1, &c1);
        s_pair[t] = make_float4(c0, c1, s0 * s1, 0.0f);
    } else {
        s_pair[t] = make_float4(0.f, 0.f, 0.f, 0.f);
    }
    __syncthreads();

    // ---- phase 2: coalesced float4 stores of this block's contiguous slab ----
    // full block slab: PPB*30 = 7680 floats = 1920 float4s = 7.5 per thread
    const int blkPairs = min(PPB, npairs - blockIdx.x * PPB);
    const int nf = blkPairs * 30;                       // floats this block owns
    float* const slab = out + (size_t)blockIdx.x * (PPB * 30);

    #pragma unroll
    for (int k = 0; k < 8; ++k) {
        const int u  = t + k * 256;                     // float4 index
        const int e0 = 4 * u;
        if (e0 < nf) {
            float v[4];
            #pragma unroll
            for (int j = 0; j < 4; ++j) {
                const int e    = e0 + j;
                const int pair = e / 30;                // magic-mul division
                const int r    = e - pair * 30;
                const float4 pd = s_pair[pair];         // one ds_read_b128
                const float2 ab = s_T[r];               // one ds_read_b64
                const float cx = (r < kC) ? pd.x : pd.y;   // register cndmask
                v[j] = fmaf(-pd.z, ab.y, fmaf(ab.x, cx, 0.5f));
            }
            if (e0 + 3 < nf) {
                *(float4*)(slab + e0) = make_float4(v[0], v[1], v[2], v[3]);
            } else {                                    // tail (unused at ref shape)
                for (int j = 0; j < 4 && e0 + j < nf; ++j) slab[e0 + j] = v[j];
            }
        }
    }
}

extern "C" void kernel_launch(void* const* d_in, const int* in_sizes, int n_in,
                              void* d_out, int out_size, void* d_ws, size_t ws_size,
                              hipStream_t stream) {
    const float* x         = (const float*)d_in[0];
    const int*   pairs_idx = (const int*)  d_in[1];
    const float* rz        = (const float*)d_in[2];
    const float* ry        = (const float*)d_in[3];
    float* out = (float*)d_out;

    const int npairs  = in_sizes[1] / 2;             // B*P = 491520
    const int nblocks = (npairs + PPB - 1) / PPB;    // 1920 at the reference shape

    hipLaunchKernelGGL(fuzzy_quantum_kernel, dim3(nblocks), dim3(256), 0, stream,
                       x, pairs_idx, rz, ry, out, npairs);
}